// Round 2
// baseline (2372.167 us; speedup 1.0000x reference)
//
#include <hip/hip_runtime.h>

#define NREPL 8   // MI355X: 8 XCDs, one accumulator replica per XCD

__device__ __forceinline__ uint32_t xcc_id() {
    uint32_t x;
    // HW_REG_XCC_ID = hwreg id 20, bits [3:0] (gfx940+; verified gfx950)
    asm volatile("s_getreg_b32 %0, hwreg(20, 0, 4)" : "=s"(x));
    return x & (NREPL - 1);
}

__device__ __forceinline__ void edge_math(
    const float* __restrict__ vertices, float p, int s, int t,
    const float* __restrict__ We, const float* __restrict__ be,
    const float* __restrict__ Wh, const float* __restrict__ bh,
    float& m0, float& m1, float& m2)
{
    float vs0 = vertices[3*s+0], vs1 = vertices[3*s+1], vs2 = vertices[3*s+2];
    float vt0 = vertices[3*t+0], vt1 = vertices[3*t+1], vt2 = vertices[3*t+2];

    // We is 6x2 row-major
    float h0 = be[0] + vs0*We[0] + vs1*We[2] + vs2*We[4]
                     + vt0*We[6] + vt1*We[8] + vt2*We[10];
    float h1 = be[1] + vs0*We[1] + vs1*We[3] + vs2*We[5]
                     + vt0*We[7] + vt1*We[9] + vt2*We[11];
    h0 *= p;
    h1 *= p;

    // Wh is 2x3 row-major
    m0 = bh[0] + h0*Wh[0] + h1*Wh[3];
    m1 = bh[1] + h0*Wh[1] + h1*Wh[4];
    m2 = bh[2] + h0*Wh[2] + h1*Wh[5];
}

// Main path: per-XCD replica, workgroup-scope atomics (execute in local TCC,
// write-back, no memory-side forwarding).
__global__ __launch_bounds__(256) void gnn_edge_xcd(
    const float* __restrict__ vertices,
    const float* __restrict__ prob,
    const int*   __restrict__ edges,
    const float* __restrict__ We, const float* __restrict__ be,
    const float* __restrict__ Wh, const float* __restrict__ bh,
    float* __restrict__ repl,    // NREPL x repl_elems, pre-zeroed
    int E, int repl_elems)
{
    int e = blockIdx.x * blockDim.x + threadIdx.x;
    if (e >= E) return;

    float* acc = repl + (size_t)xcc_id() * (size_t)repl_elems;

    int2 st = ((const int2*)edges)[e];
    float p = prob[e];
    float m0, m1, m2;
    edge_math(vertices, p, st.x, st.y, We, be, Wh, bh, m0, m1, m2);

    int t3 = 3 * st.y;
    __hip_atomic_fetch_add(&acc[t3+0], m0, __ATOMIC_RELAXED, __HIP_MEMORY_SCOPE_WORKGROUP);
    __hip_atomic_fetch_add(&acc[t3+1], m1, __ATOMIC_RELAXED, __HIP_MEMORY_SCOPE_WORKGROUP);
    __hip_atomic_fetch_add(&acc[t3+2], m2, __ATOMIC_RELAXED, __HIP_MEMORY_SCOPE_WORKGROUP);
}

// Reduce replicas + vertex transform + residual.
__global__ __launch_bounds__(256) void gnn_reduce(
    const float* __restrict__ vertices,
    const float* __restrict__ repl,
    const float* __restrict__ Wv, const float* __restrict__ bv,
    float* __restrict__ out, int n, int repl_elems)
{
    int v = blockIdx.x * blockDim.x + threadIdx.x;
    if (v >= n) return;

    float h0 = 0.f, h1 = 0.f, h2 = 0.f;
    #pragma unroll
    for (int r = 0; r < NREPL; ++r) {
        const float* a = repl + (size_t)r * (size_t)repl_elems + 3*(size_t)v;
        h0 += a[0]; h1 += a[1]; h2 += a[2];
    }

    float o0 = vertices[3*v+0] + bv[0] + h0*Wv[0] + h1*Wv[3] + h2*Wv[6];
    float o1 = vertices[3*v+1] + bv[1] + h0*Wv[1] + h1*Wv[4] + h2*Wv[7];
    float o2 = vertices[3*v+2] + bv[2] + h0*Wv[2] + h1*Wv[5] + h2*Wv[8];

    out[3*v+0] = o0;
    out[3*v+1] = o1;
    out[3*v+2] = o2;
}

// ---- Fallback path (ws too small): round-1 device-scope atomics into d_out ----
__global__ __launch_bounds__(256) void gnn_edge_dev(
    const float* __restrict__ vertices,
    const float* __restrict__ prob,
    const int*   __restrict__ edges,
    const float* __restrict__ We, const float* __restrict__ be,
    const float* __restrict__ Wh, const float* __restrict__ bh,
    float* __restrict__ acc, int E)
{
    int e = blockIdx.x * blockDim.x + threadIdx.x;
    if (e >= E) return;
    int2 st = ((const int2*)edges)[e];
    float p = prob[e];
    float m0, m1, m2;
    edge_math(vertices, p, st.x, st.y, We, be, Wh, bh, m0, m1, m2);
    int t3 = 3 * st.y;
    atomicAdd(&acc[t3+0], m0);
    atomicAdd(&acc[t3+1], m1);
    atomicAdd(&acc[t3+2], m2);
}

__global__ __launch_bounds__(256) void gnn_vertex_inplace(
    const float* __restrict__ vertices,
    const float* __restrict__ Wv, const float* __restrict__ bv,
    float* __restrict__ out, int n)
{
    int v = blockIdx.x * blockDim.x + threadIdx.x;
    if (v >= n) return;
    float h0 = out[3*v+0], h1 = out[3*v+1], h2 = out[3*v+2];
    float o0 = vertices[3*v+0] + bv[0] + h0*Wv[0] + h1*Wv[3] + h2*Wv[6];
    float o1 = vertices[3*v+1] + bv[1] + h0*Wv[1] + h1*Wv[4] + h2*Wv[7];
    float o2 = vertices[3*v+2] + bv[2] + h0*Wv[2] + h1*Wv[5] + h2*Wv[8];
    out[3*v+0] = o0; out[3*v+1] = o1; out[3*v+2] = o2;
}

extern "C" void kernel_launch(void* const* d_in, const int* in_sizes, int n_in,
                              void* d_out, int out_size, void* d_ws, size_t ws_size,
                              hipStream_t stream)
{
    const float* vertices = (const float*)d_in[0];
    const float* prob     = (const float*)d_in[1];
    const int*   edges    = (const int*)d_in[2];
    const float* We       = (const float*)d_in[3];
    const float* be       = (const float*)d_in[4];
    const float* Wh       = (const float*)d_in[5];
    const float* bh       = (const float*)d_in[6];
    const float* Wv       = (const float*)d_in[7];
    const float* bv       = (const float*)d_in[8];
    float* out = (float*)d_out;

    const int E = in_sizes[2] / 2;
    const int n = in_sizes[0] / 3;
    const int repl_elems = out_size;                      // n*3
    const size_t repl_bytes = (size_t)repl_elems * sizeof(float);
    const size_t need = repl_bytes * NREPL;

    const int eblocks = (E + 255) / 256;
    const int vblocks = (n + 255) / 256;

    if (ws_size >= need) {
        float* repl = (float*)d_ws;
        hipMemsetAsync(repl, 0, need, stream);
        gnn_edge_xcd<<<eblocks, 256, 0, stream>>>(vertices, prob, edges,
                                                  We, be, Wh, bh,
                                                  repl, E, repl_elems);
        gnn_reduce<<<vblocks, 256, 0, stream>>>(vertices, repl, Wv, bv,
                                                out, n, repl_elems);
    } else {
        hipMemsetAsync(d_out, 0, (size_t)out_size * sizeof(float), stream);
        gnn_edge_dev<<<eblocks, 256, 0, stream>>>(vertices, prob, edges,
                                                  We, be, Wh, bh, out, E);
        gnn_vertex_inplace<<<vblocks, 256, 0, stream>>>(vertices, Wv, bv, out, n);
    }
}

// Round 3
// 772.386 us; speedup vs baseline: 3.0712x; 3.0712x over previous
//
#include <hip/hip_runtime.h>
#include <math.h>

#define NBMAX 2048          // max bins (vertex-range width 256)
#define GSCAT 512           // blocks for hist/scatter passes

// ---------------- helpers ----------------

__device__ __forceinline__ void edge_math(
    float vs0, float vs1, float vs2,
    float vt0, float vt1, float vt2, float p,
    const float* __restrict__ We, const float* __restrict__ be,
    const float* __restrict__ Wh, const float* __restrict__ bh,
    float& m0, float& m1, float& m2)
{
    // We is 6x2 row-major
    float h0 = be[0] + vs0*We[0] + vs1*We[2] + vs2*We[4]
                     + vt0*We[6] + vt1*We[8] + vt2*We[10];
    float h1 = be[1] + vs0*We[1] + vs1*We[3] + vs2*We[5]
                     + vt0*We[7] + vt1*We[9] + vt2*We[11];
    h0 *= p; h1 *= p;
    // Wh is 2x3 row-major
    m0 = bh[0] + h0*Wh[0] + h1*Wh[3];
    m1 = bh[1] + h0*Wh[1] + h1*Wh[4];
    m2 = bh[2] + h0*Wh[2] + h1*Wh[5];
}

// ---------------- main path kernels ----------------

// Pad vertices (N,3) -> float4 table for single-instruction gathers.
__global__ __launch_bounds__(256) void k_pad(
    const float* __restrict__ vertices, float4* __restrict__ vtx4, int n)
{
    int v = blockIdx.x * blockDim.x + threadIdx.x;
    if (v >= n) return;
    vtx4[v] = make_float4(vertices[3*v+0], vertices[3*v+1], vertices[3*v+2], 0.f);
}

// Histogram: counts[block][bin]
__global__ __launch_bounds__(256) void k_hist(
    const int* __restrict__ edges, unsigned* __restrict__ counts,
    int E, int per_block, int NB)
{
    __shared__ unsigned hist[NBMAX];
    int tid = threadIdx.x, b = blockIdx.x;
    for (int j = tid; j < NB; j += 256) hist[j] = 0;
    __syncthreads();
    int s0 = b * per_block;
    int s1 = min(E, s0 + per_block);
    for (int i = s0 + tid; i < s1; i += 256) {
        int t = ((const int2*)edges)[i].y;
        atomicAdd(&hist[((unsigned)t) >> 8], 1u);
    }
    __syncthreads();
    for (int j = tid; j < NB; j += 256)
        counts[(size_t)b * NB + j] = hist[j];
}

// Per-bin exclusive scan over GSCAT block-counts -> absolute scatter cursors.
// startm[block][bin] = bin*cap + prefix ; binFill[bin] = total
__global__ __launch_bounds__(256) void k_scan(
    const unsigned* __restrict__ counts, unsigned* __restrict__ startm,
    unsigned* __restrict__ binFill, int NB, int cap)
{
    __shared__ unsigned c[GSCAT];
    __shared__ unsigned part[256];
    int j = blockIdx.x, tid = threadIdx.x;
    c[tid]       = counts[(size_t)tid * NB + j];
    c[tid + 256] = counts[(size_t)(tid + 256) * NB + j];
    __syncthreads();
    unsigned a0 = c[2*tid], a1 = c[2*tid+1];
    part[tid] = a0 + a1;
    __syncthreads();
    for (int off = 1; off < 256; off <<= 1) {
        unsigned u = (tid >= off) ? part[tid - off] : 0u;
        __syncthreads();
        part[tid] += u;
        __syncthreads();
    }
    unsigned incl = part[tid];
    unsigned base = (unsigned)j * (unsigned)cap;
    startm[(size_t)(2*tid)   * NB + j] = base + incl - a0 - a1;
    startm[(size_t)(2*tid+1) * NB + j] = base + incl - a1;
    if (tid == 255) binFill[j] = incl;
}

// Scatter: pack (src 19b | tl 8b, p) into 8B records, bin-contiguous.
__global__ __launch_bounds__(256) void k_scatter(
    const int* __restrict__ edges, const float* __restrict__ prob,
    const unsigned* __restrict__ startm, uint2* __restrict__ rec,
    int E, int per_block, int NB, int cap)
{
    __shared__ unsigned cur[NBMAX];
    int tid = threadIdx.x, b = blockIdx.x;
    for (int j = tid; j < NB; j += 256)
        cur[j] = startm[(size_t)b * NB + j];
    __syncthreads();
    int s0 = b * per_block;
    int s1 = min(E, s0 + per_block);
    for (int i = s0 + tid; i < s1; i += 256) {
        int2 st = ((const int2*)edges)[i];
        float p  = prob[i];
        unsigned t = (unsigned)st.y;
        unsigned bin = t >> 8, tl = t & 255u;
        unsigned pos = atomicAdd(&cur[bin], 1u);
        if (pos < (bin + 1u) * (unsigned)cap) {
            rec[pos] = make_uint2((unsigned)st.x | (tl << 19), __float_as_uint(p));
        }
    }
}

// Accumulate per bin in LDS, then fused vertex transform + residual.
__global__ __launch_bounds__(256) void k_accum(
    const float* __restrict__ vertices, const float4* __restrict__ vtx4,
    const uint2* __restrict__ rec, const unsigned* __restrict__ binFill,
    const float* __restrict__ We, const float* __restrict__ be,
    const float* __restrict__ Wh, const float* __restrict__ bh,
    const float* __restrict__ Wv, const float* __restrict__ bv,
    float* __restrict__ out, int n, int cap)
{
    __shared__ float vt[256*3];
    __shared__ float acc[256*3];
    int j = blockIdx.x, tid = threadIdx.x;
    int v0 = j << 8;
    int nv = min(256, n - v0);
    for (int k = tid; k < nv*3; k += 256) {
        vt[k]  = vertices[(size_t)v0*3 + k];
        acc[k] = 0.f;
    }
    __syncthreads();

    unsigned fill = binFill[j];
    size_t base = (size_t)j * (size_t)cap;
    for (unsigned r = tid; r < fill; r += 256) {
        uint2 rc = rec[base + r];
        unsigned s  = rc.x & 0x7FFFFu;
        unsigned tl = rc.x >> 19;
        float p = __uint_as_float(rc.y);
        float4 vs = vtx4[s];
        float m0, m1, m2;
        edge_math(vs.x, vs.y, vs.z,
                  vt[tl*3+0], vt[tl*3+1], vt[tl*3+2], p,
                  We, be, Wh, bh, m0, m1, m2);
        atomicAdd(&acc[tl*3+0], m0);
        atomicAdd(&acc[tl*3+1], m1);
        atomicAdd(&acc[tl*3+2], m2);
    }
    __syncthreads();

    if (tid < nv) {
        float h0 = acc[tid*3+0], h1 = acc[tid*3+1], h2 = acc[tid*3+2];
        float o0 = vt[tid*3+0] + bv[0] + h0*Wv[0] + h1*Wv[3] + h2*Wv[6];
        float o1 = vt[tid*3+1] + bv[1] + h0*Wv[1] + h1*Wv[4] + h2*Wv[7];
        float o2 = vt[tid*3+2] + bv[2] + h0*Wv[2] + h1*Wv[5] + h2*Wv[8];
        size_t o = (size_t)(v0 + tid) * 3;
        out[o+0] = o0; out[o+1] = o1; out[o+2] = o2;
    }
}

// ---------------- fallback path (ws too small): device atomics ----------------

__global__ __launch_bounds__(256) void gnn_edge_dev(
    const float* __restrict__ vertices, const float* __restrict__ prob,
    const int* __restrict__ edges,
    const float* __restrict__ We, const float* __restrict__ be,
    const float* __restrict__ Wh, const float* __restrict__ bh,
    float* __restrict__ acc, int E)
{
    int e = blockIdx.x * blockDim.x + threadIdx.x;
    if (e >= E) return;
    int2 st = ((const int2*)edges)[e];
    float p = prob[e];
    int s = st.x, t = st.y;
    float m0, m1, m2;
    edge_math(vertices[3*s], vertices[3*s+1], vertices[3*s+2],
              vertices[3*t], vertices[3*t+1], vertices[3*t+2], p,
              We, be, Wh, bh, m0, m1, m2);
    atomicAdd(&acc[3*t+0], m0);
    atomicAdd(&acc[3*t+1], m1);
    atomicAdd(&acc[3*t+2], m2);
}

__global__ __launch_bounds__(256) void gnn_vertex_inplace(
    const float* __restrict__ vertices,
    const float* __restrict__ Wv, const float* __restrict__ bv,
    float* __restrict__ out, int n)
{
    int v = blockIdx.x * blockDim.x + threadIdx.x;
    if (v >= n) return;
    float h0 = out[3*v+0], h1 = out[3*v+1], h2 = out[3*v+2];
    float o0 = vertices[3*v+0] + bv[0] + h0*Wv[0] + h1*Wv[3] + h2*Wv[6];
    float o1 = vertices[3*v+1] + bv[1] + h0*Wv[1] + h1*Wv[4] + h2*Wv[7];
    float o2 = vertices[3*v+2] + bv[2] + h0*Wv[2] + h1*Wv[5] + h2*Wv[8];
    out[3*v+0] = o0; out[3*v+1] = o1; out[3*v+2] = o2;
}

// ---------------- launcher ----------------

extern "C" void kernel_launch(void* const* d_in, const int* in_sizes, int n_in,
                              void* d_out, int out_size, void* d_ws, size_t ws_size,
                              hipStream_t stream)
{
    const float* vertices = (const float*)d_in[0];
    const float* prob     = (const float*)d_in[1];
    const int*   edges    = (const int*)d_in[2];
    const float* We       = (const float*)d_in[3];
    const float* be       = (const float*)d_in[4];
    const float* Wh       = (const float*)d_in[5];
    const float* bh       = (const float*)d_in[6];
    const float* Wv       = (const float*)d_in[7];
    const float* bv       = (const float*)d_in[8];
    float* out = (float*)d_out;

    const int E = in_sizes[2] / 2;
    const int n = in_sizes[0] / 3;

    const int NB = (n + 255) >> 8;                 // 256-vertex bins
    const int avg = E / NB;
    int cap = avg + 8 * (int)sqrt((double)avg);    // +8 sigma (Poisson)
    cap = (cap + 127) & ~127;

    // ws layout
    size_t off = 0;
    float4*   vtx4    = (float4*)((char*)d_ws + off); off += (size_t)n * 16;
    off = (off + 255) & ~(size_t)255;
    unsigned* counts  = (unsigned*)((char*)d_ws + off); off += (size_t)GSCAT * NB * 4;
    unsigned* startm  = (unsigned*)((char*)d_ws + off); off += (size_t)GSCAT * NB * 4;
    unsigned* binFill = (unsigned*)((char*)d_ws + off); off += (size_t)NB * 4;
    off = (off + 255) & ~(size_t)255;
    uint2*    rec     = (uint2*)((char*)d_ws + off); off += (size_t)NB * cap * 8;
    const size_t need = off;

    if (NB <= NBMAX && n < (1 << 19) && ws_size >= need) {
        const int per_block = (E + GSCAT - 1) / GSCAT;
        k_pad<<<(n + 255)/256, 256, 0, stream>>>(vertices, vtx4, n);
        k_hist<<<GSCAT, 256, 0, stream>>>(edges, counts, E, per_block, NB);
        k_scan<<<NB, 256, 0, stream>>>(counts, startm, binFill, NB, cap);
        k_scatter<<<GSCAT, 256, 0, stream>>>(edges, prob, startm, rec,
                                             E, per_block, NB, cap);
        k_accum<<<NB, 256, 0, stream>>>(vertices, vtx4, rec, binFill,
                                        We, be, Wh, bh, Wv, bv, out, n, cap);
    } else {
        hipMemsetAsync(d_out, 0, (size_t)out_size * sizeof(float), stream);
        gnn_edge_dev<<<(E + 255)/256, 256, 0, stream>>>(vertices, prob, edges,
                                                        We, be, Wh, bh, out, E);
        gnn_vertex_inplace<<<(n + 255)/256, 256, 0, stream>>>(vertices, Wv, bv, out, n);
    }
}

// Round 4
// 721.893 us; speedup vs baseline: 3.2860x; 1.0699x over previous
//
#include <hip/hip_runtime.h>
#include <math.h>

#define NBMAX 512           // max fine bins
#define GSCAT 512           // blocks for hist/scatter passes
#define BINW  1024          // vertices per bin
#define BSH   10            // log2(BINW)

// ---------------- main path kernels ----------------

// Per-vertex source projection: a[v] = v @ We_top  (2 floats, 4 MB table)
__global__ __launch_bounds__(256) void k_prep(
    const float* __restrict__ vertices, float2* __restrict__ aT,
    const float* __restrict__ We, int n)
{
    int v = blockIdx.x * blockDim.x + threadIdx.x;
    if (v >= n) return;
    float v0 = vertices[3*v], v1 = vertices[3*v+1], v2 = vertices[3*v+2];
    aT[v] = make_float2(v0*We[0] + v1*We[2] + v2*We[4],
                        v0*We[1] + v1*We[3] + v2*We[5]);
}

// Histogram of targets over NB bins: counts[block][bin]
__global__ __launch_bounds__(256) void k_hist(
    const int* __restrict__ edges, unsigned* __restrict__ counts,
    int E, int per_block, int NB)
{
    __shared__ unsigned hist[NBMAX];
    int tid = threadIdx.x, b = blockIdx.x;
    for (int j = tid; j < NB; j += 256) hist[j] = 0;
    __syncthreads();
    int s0 = b * per_block;
    int s1 = min(E, s0 + per_block);
    for (int i = s0 + tid; i < s1; i += 256) {
        int t = ((const int2*)edges)[i].y;
        atomicAdd(&hist[((unsigned)t) >> BSH], 1u);
    }
    __syncthreads();
    for (int j = tid; j < NB; j += 256)
        counts[(size_t)b * NB + j] = hist[j];
}

// Per-bin exclusive scan over GSCAT block-counts -> absolute scatter cursors.
__global__ __launch_bounds__(256) void k_scan(
    const unsigned* __restrict__ counts, unsigned* __restrict__ startm,
    unsigned* __restrict__ binFill, int NB, int cap)
{
    __shared__ unsigned c[GSCAT];
    __shared__ unsigned part[256];
    int j = blockIdx.x, tid = threadIdx.x;
    c[tid]       = counts[(size_t)tid * NB + j];
    c[tid + 256] = counts[(size_t)(tid + 256) * NB + j];
    __syncthreads();
    unsigned a0 = c[2*tid], a1 = c[2*tid+1];
    part[tid] = a0 + a1;
    __syncthreads();
    for (int off = 1; off < 256; off <<= 1) {
        unsigned u = (tid >= off) ? part[tid - off] : 0u;
        __syncthreads();
        part[tid] += u;
        __syncthreads();
    }
    unsigned incl = part[tid];
    unsigned base = (unsigned)j * (unsigned)cap;
    startm[(size_t)(2*tid)   * NB + j] = base + incl - a0 - a1;
    startm[(size_t)(2*tid+1) * NB + j] = base + incl - a1;
    if (tid == 255) binFill[j] = incl;
}

// Scatter: pack (src 19b | t_low 10b, p) into 8B records, bin-contiguous.
__global__ __launch_bounds__(256) void k_scatter(
    const int* __restrict__ edges, const float* __restrict__ prob,
    const unsigned* __restrict__ startm, uint2* __restrict__ rec,
    int E, int per_block, int NB, int cap)
{
    __shared__ unsigned cur[NBMAX];
    int tid = threadIdx.x, b = blockIdx.x;
    for (int j = tid; j < NB; j += 256)
        cur[j] = startm[(size_t)b * NB + j];
    __syncthreads();
    int s0 = b * per_block;
    int s1 = min(E, s0 + per_block);
    for (int i = s0 + tid; i < s1; i += 256) {
        int2 st = ((const int2*)edges)[i];
        float p  = prob[i];
        unsigned t = (unsigned)st.y;
        unsigned bin = t >> BSH, tl = t & (BINW - 1u);
        unsigned pos = atomicAdd(&cur[bin], 1u);
        if (pos < (bin + 1u) * (unsigned)cap) {
            rec[pos] = make_uint2((unsigned)st.x | (tl << 19), __float_as_uint(p));
        }
    }
}

// Accumulate per bin in LDS (SoA to spread banks), then fused final transform.
__global__ __launch_bounds__(256) void k_accum(
    const float* __restrict__ vertices,
    const float2* __restrict__ aT,
    const uint2* __restrict__ rec, const unsigned* __restrict__ binFill,
    const float* __restrict__ We, const float* __restrict__ be,
    const float* __restrict__ Wh, const float* __restrict__ bh,
    const float* __restrict__ Wv, const float* __restrict__ bv,
    float* __restrict__ out, int n, int cap)
{
    __shared__ float sSa0[BINW], sSa1[BINW], sP[BINW], sD[BINW];
    int j = blockIdx.x, tid = threadIdx.x;
    int v0 = j << BSH;
    int nv = min(BINW, n - v0);
    for (int k = tid; k < BINW; k += 256) {
        sSa0[k] = 0.f; sSa1[k] = 0.f; sP[k] = 0.f; sD[k] = 0.f;
    }
    __syncthreads();

    unsigned fill = binFill[j];
    size_t base = (size_t)j * (size_t)cap;
    for (unsigned r = tid; r < fill; r += 256) {
        uint2 rc = rec[base + r];
        unsigned s  = rc.x & 0x7FFFFu;
        unsigned tl = rc.x >> 19;
        float p = __uint_as_float(rc.y);
        float2 a = aT[s];
        atomicAdd(&sSa0[tl], p * a.x);
        atomicAdd(&sSa1[tl], p * a.y);
        atomicAdd(&sP[tl],  p);
        atomicAdd(&sD[tl],  1.f);
    }
    __syncthreads();

    for (int lt = tid; lt < nv; lt += 256) {
        int v = v0 + lt;
        float t0 = vertices[3*v], t1 = vertices[3*v+1], t2 = vertices[3*v+2];
        // b[t] = v_t @ We_bot  (rows 3..5 of 6x2 row-major We)
        float b0 = t0*We[6] + t1*We[8] + t2*We[10];
        float b1 = t0*We[7] + t1*We[9] + t2*We[11];
        float P = sP[lt], D = sD[lt];
        float g0 = sSa0[lt] + (b0 + be[0]) * P;
        float g1 = sSa1[lt] + (b1 + be[1]) * P;
        // h = g @ Wh + D*bh   (Wh is 2x3 row-major)
        float h0 = g0*Wh[0] + g1*Wh[3] + D*bh[0];
        float h1 = g0*Wh[1] + g1*Wh[4] + D*bh[1];
        float h2 = g0*Wh[2] + g1*Wh[5] + D*bh[2];
        out[3*v+0] = t0 + bv[0] + h0*Wv[0] + h1*Wv[3] + h2*Wv[6];
        out[3*v+1] = t1 + bv[1] + h0*Wv[1] + h1*Wv[4] + h2*Wv[7];
        out[3*v+2] = t2 + bv[2] + h0*Wv[2] + h1*Wv[5] + h2*Wv[8];
    }
}

// ---------------- fallback path (ws too small): device atomics ----------------

__device__ __forceinline__ void edge_math_full(
    const float* __restrict__ vertices, float p, int s, int t,
    const float* __restrict__ We, const float* __restrict__ be,
    const float* __restrict__ Wh, const float* __restrict__ bh,
    float& m0, float& m1, float& m2)
{
    float vs0 = vertices[3*s], vs1 = vertices[3*s+1], vs2 = vertices[3*s+2];
    float vt0 = vertices[3*t], vt1 = vertices[3*t+1], vt2 = vertices[3*t+2];
    float h0 = be[0] + vs0*We[0] + vs1*We[2] + vs2*We[4]
                     + vt0*We[6] + vt1*We[8] + vt2*We[10];
    float h1 = be[1] + vs0*We[1] + vs1*We[3] + vs2*We[5]
                     + vt0*We[7] + vt1*We[9] + vt2*We[11];
    h0 *= p; h1 *= p;
    m0 = bh[0] + h0*Wh[0] + h1*Wh[3];
    m1 = bh[1] + h0*Wh[1] + h1*Wh[4];
    m2 = bh[2] + h0*Wh[2] + h1*Wh[5];
}

__global__ __launch_bounds__(256) void gnn_edge_dev(
    const float* __restrict__ vertices, const float* __restrict__ prob,
    const int* __restrict__ edges,
    const float* __restrict__ We, const float* __restrict__ be,
    const float* __restrict__ Wh, const float* __restrict__ bh,
    float* __restrict__ acc, int E)
{
    int e = blockIdx.x * blockDim.x + threadIdx.x;
    if (e >= E) return;
    int2 st = ((const int2*)edges)[e];
    float m0, m1, m2;
    edge_math_full(vertices, prob[e], st.x, st.y, We, be, Wh, bh, m0, m1, m2);
    atomicAdd(&acc[3*st.y+0], m0);
    atomicAdd(&acc[3*st.y+1], m1);
    atomicAdd(&acc[3*st.y+2], m2);
}

__global__ __launch_bounds__(256) void gnn_vertex_inplace(
    const float* __restrict__ vertices,
    const float* __restrict__ Wv, const float* __restrict__ bv,
    float* __restrict__ out, int n)
{
    int v = blockIdx.x * blockDim.x + threadIdx.x;
    if (v >= n) return;
    float h0 = out[3*v+0], h1 = out[3*v+1], h2 = out[3*v+2];
    float o0 = vertices[3*v+0] + bv[0] + h0*Wv[0] + h1*Wv[3] + h2*Wv[6];
    float o1 = vertices[3*v+1] + bv[1] + h0*Wv[1] + h1*Wv[4] + h2*Wv[7];
    float o2 = vertices[3*v+2] + bv[2] + h0*Wv[2] + h1*Wv[5] + h2*Wv[8];
    out[3*v+0] = o0; out[3*v+1] = o1; out[3*v+2] = o2;
}

// ---------------- launcher ----------------

extern "C" void kernel_launch(void* const* d_in, const int* in_sizes, int n_in,
                              void* d_out, int out_size, void* d_ws, size_t ws_size,
                              hipStream_t stream)
{
    const float* vertices = (const float*)d_in[0];
    const float* prob     = (const float*)d_in[1];
    const int*   edges    = (const int*)d_in[2];
    const float* We       = (const float*)d_in[3];
    const float* be       = (const float*)d_in[4];
    const float* Wh       = (const float*)d_in[5];
    const float* bh       = (const float*)d_in[6];
    const float* Wv       = (const float*)d_in[7];
    const float* bv       = (const float*)d_in[8];
    float* out = (float*)d_out;

    const int E = in_sizes[2] / 2;
    const int n = in_sizes[0] / 3;

    const int NB = (n + BINW - 1) >> BSH;          // 1024-vertex bins
    const int avg = E / NB;
    int cap = avg + 8 * (int)sqrt((double)avg);    // +8 sigma
    cap = (cap + 127) & ~127;

    // ws layout
    size_t off = 0;
    float2*   aT      = (float2*)((char*)d_ws + off); off += (size_t)n * 8;
    off = (off + 255) & ~(size_t)255;
    unsigned* counts  = (unsigned*)((char*)d_ws + off); off += (size_t)GSCAT * NB * 4;
    unsigned* startm  = (unsigned*)((char*)d_ws + off); off += (size_t)GSCAT * NB * 4;
    unsigned* binFill = (unsigned*)((char*)d_ws + off); off += (size_t)NB * 4;
    off = (off + 255) & ~(size_t)255;
    uint2*    rec     = (uint2*)((char*)d_ws + off); off += (size_t)NB * cap * 8;
    const size_t need = off;

    if (NB <= NBMAX && n < (1 << 19) && ws_size >= need) {
        const int per_block = (E + GSCAT - 1) / GSCAT;
        k_prep<<<(n + 255)/256, 256, 0, stream>>>(vertices, aT, We, n);
        k_hist<<<GSCAT, 256, 0, stream>>>(edges, counts, E, per_block, NB);
        k_scan<<<NB, 256, 0, stream>>>(counts, startm, binFill, NB, cap);
        k_scatter<<<GSCAT, 256, 0, stream>>>(edges, prob, startm, rec,
                                             E, per_block, NB, cap);
        k_accum<<<NB, 256, 0, stream>>>(vertices, aT, rec, binFill,
                                        We, be, Wh, bh, Wv, bv, out, n, cap);
    } else {
        hipMemsetAsync(d_out, 0, (size_t)out_size * sizeof(float), stream);
        gnn_edge_dev<<<(E + 255)/256, 256, 0, stream>>>(vertices, prob, edges,
                                                        We, be, Wh, bh, out, E);
        gnn_vertex_inplace<<<(n + 255)/256, 256, 0, stream>>>(vertices, Wv, bv, out, n);
    }
}

// Round 5
// 609.677 us; speedup vs baseline: 3.8909x; 1.1841x over previous
//
#include <hip/hip_runtime.h>
#include <math.h>

#define NBMAX 512           // max fine bins
#define GSCAT 512           // blocks for hist/scatter passes
#define BINW  1024          // vertices per bin
#define BSH   10            // log2(BINW)
#define TBIG  1024          // big block size for hist/scatter/accum

// ---------------- main path kernels ----------------

// Per-vertex source projection, packed bf16x2: a[v] = v @ We_top
__global__ __launch_bounds__(256) void k_prep(
    const float* __restrict__ vertices, unsigned* __restrict__ aTp,
    const float* __restrict__ We, int n)
{
    int v = blockIdx.x * blockDim.x + threadIdx.x;
    if (v >= n) return;
    float v0 = vertices[3*v], v1 = vertices[3*v+1], v2 = vertices[3*v+2];
    float a0 = v0*We[0] + v1*We[2] + v2*We[4];
    float a1 = v0*We[1] + v1*We[3] + v2*We[5];
    unsigned u0 = __float_as_uint(a0);
    unsigned u1 = __float_as_uint(a1);
    u0 += 0x7FFFu + ((u0 >> 16) & 1u);   // RNE to bf16
    u1 += 0x7FFFu + ((u1 >> 16) & 1u);
    aTp[v] = (u0 >> 16) | (u1 & 0xFFFF0000u);
}

// Histogram of targets over NB bins: counts[block][bin]
__global__ __launch_bounds__(TBIG) void k_hist(
    const int* __restrict__ edges, unsigned* __restrict__ counts,
    int E, int per_block, int NB)
{
    __shared__ unsigned hist[NBMAX];
    int tid = threadIdx.x, b = blockIdx.x;
    for (int j = tid; j < NB; j += TBIG) hist[j] = 0;
    __syncthreads();
    int s0 = b * per_block;
    int s1 = min(E, s0 + per_block);
    int cnt = s1 - s0;
    if (cnt > 0) {
        int npair = cnt >> 1;
        for (int k = tid; k < npair; k += TBIG) {
            int4 e2 = *(const int4*)&edges[2*(s0 + 2*k)];
            atomicAdd(&hist[((unsigned)e2.y) >> BSH], 1u);
            atomicAdd(&hist[((unsigned)e2.w) >> BSH], 1u);
        }
        if ((cnt & 1) && tid == 0) {
            int t = ((const int2*)edges)[s1 - 1].y;
            atomicAdd(&hist[((unsigned)t) >> BSH], 1u);
        }
    }
    __syncthreads();
    for (int j = tid; j < NB; j += TBIG)
        counts[(size_t)b * NB + j] = hist[j];
}

// Per-bin exclusive scan over GSCAT block-counts -> absolute scatter cursors.
__global__ __launch_bounds__(256) void k_scan(
    const unsigned* __restrict__ counts, unsigned* __restrict__ startm,
    unsigned* __restrict__ binFill, int NB, int cap)
{
    __shared__ unsigned c[GSCAT];
    __shared__ unsigned part[256];
    int j = blockIdx.x, tid = threadIdx.x;
    c[tid]       = counts[(size_t)tid * NB + j];
    c[tid + 256] = counts[(size_t)(tid + 256) * NB + j];
    __syncthreads();
    unsigned a0 = c[2*tid], a1 = c[2*tid+1];
    part[tid] = a0 + a1;
    __syncthreads();
    for (int off = 1; off < 256; off <<= 1) {
        unsigned u = (tid >= off) ? part[tid - off] : 0u;
        __syncthreads();
        part[tid] += u;
        __syncthreads();
    }
    unsigned incl = part[tid];
    unsigned base = (unsigned)j * (unsigned)cap;
    startm[(size_t)(2*tid)   * NB + j] = base + incl - a0 - a1;
    startm[(size_t)(2*tid+1) * NB + j] = base + incl - a1;
    if (tid == 255) binFill[j] = incl;
}

// Scatter: pack (src 19b | t_low 10b, p) into 8B records, bin-contiguous.
__global__ __launch_bounds__(TBIG) void k_scatter(
    const int* __restrict__ edges, const float* __restrict__ prob,
    const unsigned* __restrict__ startm, uint2* __restrict__ rec,
    int E, int per_block, int NB, int cap)
{
    __shared__ unsigned cur[NBMAX];
    int tid = threadIdx.x, b = blockIdx.x;
    for (int j = tid; j < NB; j += TBIG)
        cur[j] = startm[(size_t)b * NB + j];
    __syncthreads();
    int s0 = b * per_block;
    int s1 = min(E, s0 + per_block);
    int cnt = s1 - s0;
    if (cnt <= 0) return;
    int npair = cnt >> 1;
    unsigned capu = (unsigned)cap;
    for (int k = tid; k < npair; k += TBIG) {
        int i = s0 + 2*k;
        int4   e2 = *(const int4*)&edges[2*i];
        float2 p2 = *(const float2*)&prob[i];
        {
            unsigned t = (unsigned)e2.y;
            unsigned bin = t >> BSH, tl = t & (BINW - 1u);
            unsigned pos = atomicAdd(&cur[bin], 1u);
            if (pos < (bin + 1u) * capu)
                rec[pos] = make_uint2((unsigned)e2.x | (tl << 19), __float_as_uint(p2.x));
        }
        {
            unsigned t = (unsigned)e2.w;
            unsigned bin = t >> BSH, tl = t & (BINW - 1u);
            unsigned pos = atomicAdd(&cur[bin], 1u);
            if (pos < (bin + 1u) * capu)
                rec[pos] = make_uint2((unsigned)e2.z | (tl << 19), __float_as_uint(p2.y));
        }
    }
    if ((cnt & 1) && tid == 0) {
        int i = s1 - 1;
        int2 st = ((const int2*)edges)[i];
        float p = prob[i];
        unsigned t = (unsigned)st.y;
        unsigned bin = t >> BSH, tl = t & (BINW - 1u);
        unsigned pos = atomicAdd(&cur[bin], 1u);
        if (pos < (bin + 1u) * capu)
            rec[pos] = make_uint2((unsigned)st.x | (tl << 19), __float_as_uint(p));
    }
}

// Accumulate per bin in LDS, then fused final transform.
__global__ __launch_bounds__(TBIG) void k_accum(
    const float* __restrict__ vertices,
    const unsigned* __restrict__ aTp,
    const uint2* __restrict__ rec, const unsigned* __restrict__ binFill,
    const float* __restrict__ We, const float* __restrict__ be,
    const float* __restrict__ Wh, const float* __restrict__ bh,
    const float* __restrict__ Wv, const float* __restrict__ bv,
    float* __restrict__ out, int n, int cap)
{
    __shared__ float sSa0[BINW], sSa1[BINW], sP[BINW], sD[BINW];
    int j = blockIdx.x, tid = threadIdx.x;
    int v0 = j << BSH;
    int nv = min(BINW, n - v0);
    for (int k = tid; k < BINW; k += TBIG) {
        sSa0[k] = 0.f; sSa1[k] = 0.f; sP[k] = 0.f; sD[k] = 0.f;
    }
    __syncthreads();

    unsigned fill = binFill[j];
    const uint2* r2 = rec + (size_t)j * (size_t)cap;
    unsigned npair = fill >> 1;
    for (unsigned k = tid; k < npair; k += TBIG) {
        uint4 rc = ((const uint4*)r2)[k];
        // record 0
        {
            unsigned s  = rc.x & 0x7FFFFu;
            unsigned tl = rc.x >> 19;
            float p = __uint_as_float(rc.y);
            unsigned pk = aTp[s];
            float a0 = __uint_as_float(pk << 16);
            float a1 = __uint_as_float(pk & 0xFFFF0000u);
            atomicAdd(&sSa0[tl], p * a0);
            atomicAdd(&sSa1[tl], p * a1);
            atomicAdd(&sP[tl],  p);
            atomicAdd(&sD[tl],  1.f);
        }
        // record 1
        {
            unsigned s  = rc.z & 0x7FFFFu;
            unsigned tl = rc.z >> 19;
            float p = __uint_as_float(rc.w);
            unsigned pk = aTp[s];
            float a0 = __uint_as_float(pk << 16);
            float a1 = __uint_as_float(pk & 0xFFFF0000u);
            atomicAdd(&sSa0[tl], p * a0);
            atomicAdd(&sSa1[tl], p * a1);
            atomicAdd(&sP[tl],  p);
            atomicAdd(&sD[tl],  1.f);
        }
    }
    if ((fill & 1) && tid == 0) {
        uint2 rc = r2[fill - 1];
        unsigned s  = rc.x & 0x7FFFFu;
        unsigned tl = rc.x >> 19;
        float p = __uint_as_float(rc.y);
        unsigned pk = aTp[s];
        float a0 = __uint_as_float(pk << 16);
        float a1 = __uint_as_float(pk & 0xFFFF0000u);
        atomicAdd(&sSa0[tl], p * a0);
        atomicAdd(&sSa1[tl], p * a1);
        atomicAdd(&sP[tl],  p);
        atomicAdd(&sD[tl],  1.f);
    }
    __syncthreads();

    if (tid < nv) {
        int v = v0 + tid;
        float t0 = vertices[3*v], t1 = vertices[3*v+1], t2 = vertices[3*v+2];
        // b[t] = v_t @ We_bot  (rows 3..5 of 6x2 row-major We)
        float b0 = t0*We[6] + t1*We[8] + t2*We[10];
        float b1 = t0*We[7] + t1*We[9] + t2*We[11];
        float P = sP[tid], D = sD[tid];
        float g0 = sSa0[tid] + (b0 + be[0]) * P;
        float g1 = sSa1[tid] + (b1 + be[1]) * P;
        // h = g @ Wh + D*bh   (Wh is 2x3 row-major)
        float h0 = g0*Wh[0] + g1*Wh[3] + D*bh[0];
        float h1 = g0*Wh[1] + g1*Wh[4] + D*bh[1];
        float h2 = g0*Wh[2] + g1*Wh[5] + D*bh[2];
        out[3*v+0] = t0 + bv[0] + h0*Wv[0] + h1*Wv[3] + h2*Wv[6];
        out[3*v+1] = t1 + bv[1] + h0*Wv[1] + h1*Wv[4] + h2*Wv[7];
        out[3*v+2] = t2 + bv[2] + h0*Wv[2] + h1*Wv[5] + h2*Wv[8];
    }
}

// ---------------- fallback path (ws too small): device atomics ----------------

__device__ __forceinline__ void edge_math_full(
    const float* __restrict__ vertices, float p, int s, int t,
    const float* __restrict__ We, const float* __restrict__ be,
    const float* __restrict__ Wh, const float* __restrict__ bh,
    float& m0, float& m1, float& m2)
{
    float vs0 = vertices[3*s], vs1 = vertices[3*s+1], vs2 = vertices[3*s+2];
    float vt0 = vertices[3*t], vt1 = vertices[3*t+1], vt2 = vertices[3*t+2];
    float h0 = be[0] + vs0*We[0] + vs1*We[2] + vs2*We[4]
                     + vt0*We[6] + vt1*We[8] + vt2*We[10];
    float h1 = be[1] + vs0*We[1] + vs1*We[3] + vs2*We[5]
                     + vt0*We[7] + vt1*We[9] + vt2*We[11];
    h0 *= p; h1 *= p;
    m0 = bh[0] + h0*Wh[0] + h1*Wh[3];
    m1 = bh[1] + h0*Wh[1] + h1*Wh[4];
    m2 = bh[2] + h0*Wh[2] + h1*Wh[5];
}

__global__ __launch_bounds__(256) void gnn_edge_dev(
    const float* __restrict__ vertices, const float* __restrict__ prob,
    const int* __restrict__ edges,
    const float* __restrict__ We, const float* __restrict__ be,
    const float* __restrict__ Wh, const float* __restrict__ bh,
    float* __restrict__ acc, int E)
{
    int e = blockIdx.x * blockDim.x + threadIdx.x;
    if (e >= E) return;
    int2 st = ((const int2*)edges)[e];
    float m0, m1, m2;
    edge_math_full(vertices, prob[e], st.x, st.y, We, be, Wh, bh, m0, m1, m2);
    atomicAdd(&acc[3*st.y+0], m0);
    atomicAdd(&acc[3*st.y+1], m1);
    atomicAdd(&acc[3*st.y+2], m2);
}

__global__ __launch_bounds__(256) void gnn_vertex_inplace(
    const float* __restrict__ vertices,
    const float* __restrict__ Wv, const float* __restrict__ bv,
    float* __restrict__ out, int n)
{
    int v = blockIdx.x * blockDim.x + threadIdx.x;
    if (v >= n) return;
    float h0 = out[3*v+0], h1 = out[3*v+1], h2 = out[3*v+2];
    float o0 = vertices[3*v+0] + bv[0] + h0*Wv[0] + h1*Wv[3] + h2*Wv[6];
    float o1 = vertices[3*v+1] + bv[1] + h0*Wv[1] + h1*Wv[4] + h2*Wv[7];
    float o2 = vertices[3*v+2] + bv[2] + h0*Wv[2] + h1*Wv[5] + h2*Wv[8];
    out[3*v+0] = o0; out[3*v+1] = o1; out[3*v+2] = o2;
}

// ---------------- launcher ----------------

extern "C" void kernel_launch(void* const* d_in, const int* in_sizes, int n_in,
                              void* d_out, int out_size, void* d_ws, size_t ws_size,
                              hipStream_t stream)
{
    const float* vertices = (const float*)d_in[0];
    const float* prob     = (const float*)d_in[1];
    const int*   edges    = (const int*)d_in[2];
    const float* We       = (const float*)d_in[3];
    const float* be       = (const float*)d_in[4];
    const float* Wh       = (const float*)d_in[5];
    const float* bh       = (const float*)d_in[6];
    const float* Wv       = (const float*)d_in[7];
    const float* bv       = (const float*)d_in[8];
    float* out = (float*)d_out;

    const int E = in_sizes[2] / 2;
    const int n = in_sizes[0] / 3;

    const int NB = (n + BINW - 1) >> BSH;          // 1024-vertex bins
    const int avg = E / NB;
    int cap = avg + 8 * (int)sqrt((double)avg);    // +8 sigma
    cap = (cap + 127) & ~127;

    // ws layout
    size_t off = 0;
    unsigned* aTp     = (unsigned*)((char*)d_ws + off); off += (size_t)n * 4;
    off = (off + 255) & ~(size_t)255;
    unsigned* counts  = (unsigned*)((char*)d_ws + off); off += (size_t)GSCAT * NB * 4;
    unsigned* startm  = (unsigned*)((char*)d_ws + off); off += (size_t)GSCAT * NB * 4;
    unsigned* binFill = (unsigned*)((char*)d_ws + off); off += (size_t)NB * 4;
    off = (off + 255) & ~(size_t)255;
    uint2*    rec     = (uint2*)((char*)d_ws + off); off += (size_t)NB * cap * 8;
    const size_t need = off;

    if (NB <= NBMAX && n < (1 << 19) && ws_size >= need) {
        int per_block = (E + GSCAT - 1) / GSCAT;
        per_block = (per_block + 1) & ~1;          // even, for int4/float2 alignment
        k_prep<<<(n + 255)/256, 256, 0, stream>>>(vertices, aTp, We, n);
        k_hist<<<GSCAT, TBIG, 0, stream>>>(edges, counts, E, per_block, NB);
        k_scan<<<NB, 256, 0, stream>>>(counts, startm, binFill, NB, cap);
        k_scatter<<<GSCAT, TBIG, 0, stream>>>(edges, prob, startm, rec,
                                              E, per_block, NB, cap);
        k_accum<<<NB, TBIG, 0, stream>>>(vertices, aTp, rec, binFill,
                                         We, be, Wh, bh, Wv, bv, out, n, cap);
    } else {
        hipMemsetAsync(d_out, 0, (size_t)out_size * sizeof(float), stream);
        gnn_edge_dev<<<(E + 255)/256, 256, 0, stream>>>(vertices, prob, edges,
                                                        We, be, Wh, bh, out, E);
        gnn_vertex_inplace<<<(n + 255)/256, 256, 0, stream>>>(vertices, Wv, bv, out, n);
    }
}